// Round 1
// baseline (21252.431 us; speedup 1.0000x reference)
//
#include <hip/hip_runtime.h>
#include <hip/hip_fp16.h>

typedef _Float16 half8 __attribute__((ext_vector_type(8)));
typedef float    float4_ __attribute__((ext_vector_type(4)));

#define TSTEPS 512
#define NA 64
#define NB 128
#define NC 8
#define NBLK (NA + NB + NC)
#define NSLOTS (TSTEPS + 2)

// workspace layout (bytes)
#define BAR_OFF   0
#define H1_OFF    256
#define H1_PHASE  262144          // 1024 cols x 128 batch x 2B, fragment-major
#define H2_OFF    (H1_OFF + 2 * H1_PHASE)
#define X_OFF     (H2_OFF + 2 * H1_PHASE)
#define X_TSTRIDE 16384           // 64 cols x 128 batch x 2B per step
#define ZERO_BYTES X_OFF          // bar + H1 + H2 must be zeroed each call

__device__ __forceinline__ float sigf(float x) { return 1.0f / (1.0f + __expf(-x)); }

__device__ __forceinline__ half8 zero8() {
    half8 z;
#pragma unroll
    for (int j = 0; j < 8; ++j) z[j] = (_Float16)0.0f;
    return z;
}

// Load one B-operand fragment (8 consecutive k of one weight row) from fp32
// weights, converting to fp16. Row covers K = [0,split) from Wa, rest from Wb.
__device__ __forceinline__ half8 wfrag_load(const float* Wa, int lda,
                                            const float* Wb, int ldb,
                                            int split, int row, int k0) {
    const float* s = (k0 < split) ? (Wa + (size_t)row * lda + k0)
                                  : (Wb + (size_t)row * ldb + (k0 - split));
    float4_ lo = *(const float4_*)s;
    float4_ hi = *(const float4_*)(s + 4);
    half8 r;
    r[0] = (_Float16)lo[0]; r[1] = (_Float16)lo[1];
    r[2] = (_Float16)lo[2]; r[3] = (_Float16)lo[3];
    r[4] = (_Float16)hi[0]; r[5] = (_Float16)hi[1];
    r[6] = (_Float16)hi[2]; r[7] = (_Float16)hi[3];
    return r;
}

// Epoch-based grid barrier (all NBLK blocks co-resident: 1 block/CU, 200 <= 256 CUs).
__device__ __forceinline__ void slot_barrier(unsigned* bar, unsigned target) {
    __syncthreads();
    if (threadIdx.x == 0) {
        __hip_atomic_fetch_add(bar, 1u, __ATOMIC_RELEASE, __HIP_MEMORY_SCOPE_AGENT);
        while (__hip_atomic_load(bar, __ATOMIC_RELAXED, __HIP_MEMORY_SCOPE_AGENT) < target)
            __builtin_amdgcn_s_sleep(2);
        (void)__hip_atomic_load(bar, __ATOMIC_ACQUIRE, __HIP_MEMORY_SCOPE_AGENT);
    }
    __syncthreads();
}

// Convert input [128 b][512 t][64 i] fp32 -> fragment-major fp16 X[t][kt][quad][b][j]
extern "C" __global__ void prep_x(const float* __restrict__ in, char* __restrict__ ws) {
    const int t = blockIdx.x;
    char* X = ws + X_OFF + (size_t)t * X_TSTRIDE;
    for (int idx = threadIdx.x; idx < 8192; idx += 256) {
        int kt = idx >> 12, rem = idx & 4095;
        int quad = rem >> 10, rem2 = rem & 1023;
        int b = rem2 >> 3, j = rem2 & 7;
        int i = kt * 32 + quad * 8 + j;
        float v = in[(size_t)b * 32768 + (size_t)t * 64 + i];
        *(_Float16*)(X + (size_t)idx * 2) = (_Float16)v;
    }
}

extern "C" __global__ __launch_bounds__(256, 1)
void lstm_persistent(const float* __restrict__ Wih1, const float* __restrict__ Whh1,
                     const float* __restrict__ bih1, const float* __restrict__ bhh1,
                     const float* __restrict__ Wih2, const float* __restrict__ Whh2,
                     const float* __restrict__ bih2, const float* __restrict__ bhh2,
                     const float* __restrict__ Wout, const float* __restrict__ bout,
                     char* __restrict__ ws, float* __restrict__ out) {
    const int tid = threadIdx.x;
    const int w = tid >> 6, lane = tid & 63;
    const int quad = lane >> 4, cl = lane & 15;
    const int laneoff = quad * 2048 + cl * 16;   // byte offset of lane's A-frag within a k-tile
    unsigned* bar = (unsigned*)(ws + BAR_OFF);
    char* H1 = ws + H1_OFF;
    char* H2 = ws + H2_OFF;
    char* X  = ws + X_OFF;
    const int blk = blockIdx.x;
    __shared__ float redbuf[8192];   // 32 KB cross-wave reduction buffer

    if (blk < NA) {
        // ---------- layer-1 group: h1 cols [c0, c0+16), 64 gate rows, K = 1088 (34 k-tiles)
        const int c0 = blk * 16;
        const int kbase = w * 9;                 // K split over 4 waves: 9/9/9/9 (2 dummy)
        half8 wfr[4][9];
#pragma unroll
        for (int nt = 0; nt < 4; ++nt) {
            int row = nt * 1024 + c0 + cl;
#pragma unroll
            for (int kk = 0; kk < 9; ++kk) {
                int ktg = kbase + kk;
                if (ktg < 34) wfr[nt][kk] = wfrag_load(Wih1, 64, Whh1, 1024, 64, row, ktg * 32 + quad * 8);
                else          wfr[nt][kk] = zero8();
            }
        }
        float ba[4];
#pragma unroll
        for (int g = 0; g < 4; ++g) ba[g] = bih1[g * 1024 + c0 + cl] + bhh1[g * 1024 + c0 + cl];
        float cst[2][4];
#pragma unroll
        for (int mi = 0; mi < 2; ++mi)
#pragma unroll
            for (int r = 0; r < 4; ++r) cst[mi][r] = 0.0f;
        const int cc = c0 + cl;                  // h1 column this lane owns in epilogue
        const int woffbase = (cc >> 5) * 8192 + ((cc >> 3) & 3) * 2048 + (cc & 7) * 2;

        for (int s = 0; s < NSLOTS; ++s) {
            if (s < TSTEPS) {
                const int t = s;
                const char* xb  = X + (size_t)t * X_TSTRIDE;
                const char* h1r = H1 + (((t & 1) ^ 1) ? H1_PHASE : 0);
                char*       h1w = H1 + ((t & 1) ? H1_PHASE : 0);
                const char* kb[9];
#pragma unroll
                for (int kk = 0; kk < 9; ++kk) {
                    int ktg = kbase + kk; if (ktg > 33) ktg = 33;
                    kb[kk] = (ktg < 2) ? (xb + ktg * 8192) : (h1r + (ktg - 2) * 8192);
                }
                float4_ acc[8][4];
#pragma unroll
                for (int mt = 0; mt < 8; ++mt)
#pragma unroll
                    for (int nt = 0; nt < 4; ++nt) acc[mt][nt] = (float4_){0.f, 0.f, 0.f, 0.f};
                half8 af[2][9];
#pragma unroll
                for (int kk = 0; kk < 9; ++kk) af[0][kk] = *(const half8*)(kb[kk] + laneoff);
#pragma unroll
                for (int mt = 0; mt < 8; ++mt) {
                    const int cur = mt & 1;
                    if (mt < 7) {
#pragma unroll
                        for (int kk = 0; kk < 9; ++kk)
                            af[cur ^ 1][kk] = *(const half8*)(kb[kk] + laneoff + (mt + 1) * 256);
                    }
#pragma unroll
                    for (int kk = 0; kk < 9; ++kk)
#pragma unroll
                        for (int nt = 0; nt < 4; ++nt)
                            acc[mt][nt] = __builtin_amdgcn_mfma_f32_16x16x32_f16(
                                af[cur][kk], wfr[nt][kk], acc[mt][nt], 0, 0, 0);
                }
                // cross-wave K reduction, 4 rounds (owner wave r folds m-tiles {2r,2r+1})
#pragma unroll
                for (int r = 0; r < 4; ++r) {
                    if (w != r) {
#pragma unroll
                        for (int mi = 0; mi < 2; ++mi)
#pragma unroll
                            for (int nt = 0; nt < 4; ++nt)
                                *(float4_*)&redbuf[(((w * 2 + mi) * 4 + nt) * 64 + lane) * 4] = acc[2 * r + mi][nt];
                    }
                    __syncthreads();
                    if (w == r) {
#pragma unroll
                        for (int wo = 0; wo < 4; ++wo) if (wo != r) {
#pragma unroll
                            for (int mi = 0; mi < 2; ++mi)
#pragma unroll
                                for (int nt = 0; nt < 4; ++nt)
                                    acc[2 * r + mi][nt] += *(const float4_*)&redbuf[(((wo * 2 + mi) * 4 + nt) * 64 + lane) * 4];
                        }
                    }
                    __syncthreads();
                }
                float4_ mine[2][4];
#pragma unroll
                for (int r = 0; r < 4; ++r) if (w == r) {
#pragma unroll
                    for (int mi = 0; mi < 2; ++mi)
#pragma unroll
                        for (int nt = 0; nt < 4; ++nt) mine[mi][nt] = acc[2 * r + mi][nt];
                }
                // epilogue: LSTM cell for my 8 batch rows x my column
#pragma unroll
                for (int mi = 0; mi < 2; ++mi) {
#pragma unroll
                    for (int r = 0; r < 4; ++r) {
                        float iv = mine[mi][0][r] + ba[0];
                        float fv = mine[mi][1][r] + ba[1];
                        float gv = mine[mi][2][r] + ba[2];
                        float ov = mine[mi][3][r] + ba[3];
                        float c = sigf(fv) * cst[mi][r] + sigf(iv) * tanhf(gv);
                        float h = sigf(ov) * tanhf(c);
                        cst[mi][r] = c;
                        int m = (2 * w + mi) * 16 + quad * 4 + r;
                        *(_Float16*)(h1w + woffbase + m * 16) = (_Float16)h;
                    }
                }
            }
            slot_barrier(bar, (unsigned)(s + 1) * NBLK);
        }
    } else if (blk < NA + NB) {
        // ---------- layer-2 group: h2 cols [c0, c0+8), 32 gate rows, K = 2048 (64 k-tiles)
        const int bb = blk - NA;
        const int c0 = bb * 8;
        const int kbase = w * 16;
        const int colB = c0 + (cl & 7);
        const int row0 = (cl < 8) ? colB : (1024 + colB);          // [i | f]
        const int row1 = (cl < 8) ? (2048 + colB) : (3072 + colB); // [g | o]
        half8 wfr[2][16];
#pragma unroll
        for (int kk = 0; kk < 16; ++kk) {
            int k0 = (kbase + kk) * 32 + quad * 8;
            wfr[0][kk] = wfrag_load(Wih2, 1024, Whh2, 1024, 1024, row0, k0);
            wfr[1][kk] = wfrag_load(Wih2, 1024, Whh2, 1024, 1024, row1, k0);
        }
        const float bi = bih2[colB] + bhh2[colB];
        const float bf = bih2[1024 + colB] + bhh2[1024 + colB];
        const float bg = bih2[2048 + colB] + bhh2[2048 + colB];
        const float bo = bih2[3072 + colB] + bhh2[3072 + colB];
        float cst[2][4];
#pragma unroll
        for (int mi = 0; mi < 2; ++mi)
#pragma unroll
            for (int r = 0; r < 4; ++r) cst[mi][r] = 0.0f;
        const int woffbase = (c0 >> 5) * 8192 + ((c0 >> 3) & 3) * 2048 + (cl & 7) * 2;
        const bool lolane = (cl & 8) == 0;

        for (int s = 0; s < NSLOTS; ++s) {
            if (s >= 1 && s <= TSTEPS) {
                const int t = s - 1;
                const char* h1c = H1 + ((t & 1) ? H1_PHASE : 0);
                const char* h2r = H2 + (((t & 1) ^ 1) ? H1_PHASE : 0);
                char*       h2w = H2 + ((t & 1) ? H1_PHASE : 0);
                const char* kb[16];
#pragma unroll
                for (int kk = 0; kk < 16; ++kk) {
                    int ktg = kbase + kk;
                    kb[kk] = (ktg < 32) ? (h1c + ktg * 8192) : (h2r + (ktg - 32) * 8192);
                }
                float4_ acc[8][2];
#pragma unroll
                for (int mt = 0; mt < 8; ++mt) {
                    acc[mt][0] = (float4_){0.f, 0.f, 0.f, 0.f};
                    acc[mt][1] = (float4_){0.f, 0.f, 0.f, 0.f};
                }
                half8 af[2][16];
#pragma unroll
                for (int kk = 0; kk < 16; ++kk) af[0][kk] = *(const half8*)(kb[kk] + laneoff);
#pragma unroll
                for (int mt = 0; mt < 8; ++mt) {
                    const int cur = mt & 1;
                    if (mt < 7) {
#pragma unroll
                        for (int kk = 0; kk < 16; ++kk)
                            af[cur ^ 1][kk] = *(const half8*)(kb[kk] + laneoff + (mt + 1) * 256);
                    }
#pragma unroll
                    for (int kk = 0; kk < 16; ++kk) {
                        acc[mt][0] = __builtin_amdgcn_mfma_f32_16x16x32_f16(af[cur][kk], wfr[0][kk], acc[mt][0], 0, 0, 0);
                        acc[mt][1] = __builtin_amdgcn_mfma_f32_16x16x32_f16(af[cur][kk], wfr[1][kk], acc[mt][1], 0, 0, 0);
                    }
                }
#pragma unroll
                for (int r = 0; r < 4; ++r) {
                    if (w != r) {
#pragma unroll
                        for (int mi = 0; mi < 2; ++mi)
#pragma unroll
                            for (int nt = 0; nt < 2; ++nt)
                                *(float4_*)&redbuf[(((w * 2 + mi) * 2 + nt) * 64 + lane) * 4] = acc[2 * r + mi][nt];
                    }
                    __syncthreads();
                    if (w == r) {
#pragma unroll
                        for (int wo = 0; wo < 4; ++wo) if (wo != r) {
#pragma unroll
                            for (int mi = 0; mi < 2; ++mi)
#pragma unroll
                                for (int nt = 0; nt < 2; ++nt)
                                    acc[2 * r + mi][nt] += *(const float4_*)&redbuf[(((wo * 2 + mi) * 2 + nt) * 64 + lane) * 4];
                        }
                    }
                    __syncthreads();
                }
                float4_ mine[2][2];
#pragma unroll
                for (int r = 0; r < 4; ++r) if (w == r) {
#pragma unroll
                    for (int mi = 0; mi < 2; ++mi) {
                        mine[mi][0] = acc[2 * r + mi][0];
                        mine[mi][1] = acc[2 * r + mi][1];
                    }
                }
#pragma unroll
                for (int mi = 0; mi < 2; ++mi) {
#pragma unroll
                    for (int r = 0; r < 4; ++r) {
                        float d0 = mine[mi][0][r], d1 = mine[mi][1][r];
                        float s0 = __shfl_xor(d0, 8, 64);
                        float s1 = __shfl_xor(d1, 8, 64);
                        float iv = (lolane ? d0 : s0) + bi;
                        float fv = (lolane ? s0 : d0) + bf;
                        float gv = (lolane ? d1 : s1) + bg;
                        float ov = (lolane ? s1 : d1) + bo;
                        float c = sigf(fv) * cst[mi][r] + sigf(iv) * tanhf(gv);
                        float h = sigf(ov) * tanhf(c);
                        cst[mi][r] = c;
                        if (lolane) {
                            int m = (2 * w + mi) * 16 + quad * 4 + r;
                            *(_Float16*)(h2w + woffbase + m * 16) = (_Float16)h;
                        }
                    }
                }
            }
            slot_barrier(bar, (unsigned)(s + 1) * NBLK);
        }
    } else {
        // ---------- output group: batch tile cb, y = h2 @ Wout^T + bout, K = 1024 (32 k-tiles)
        const int cb = blk - NA - NB;
        const int kbase = w * 8;
        half8 wfr[4][8];
#pragma unroll
        for (int nt = 0; nt < 4; ++nt) {
            int row = nt * 16 + cl;
#pragma unroll
            for (int kk = 0; kk < 8; ++kk)
                wfr[nt][kk] = wfrag_load(Wout, 1024, Wout, 1024, 1 << 30, row, (kbase + kk) * 32 + quad * 8);
        }
        const float bo_ = bout[w * 16 + cl];

        for (int s = 0; s < NSLOTS; ++s) {
            if (s >= 2) {
                const int t = s - 2;
                const char* h2c = H2 + ((t & 1) ? H1_PHASE : 0);
                float4_ acc[4];
#pragma unroll
                for (int nt = 0; nt < 4; ++nt) acc[nt] = (float4_){0.f, 0.f, 0.f, 0.f};
                half8 af[8];
#pragma unroll
                for (int kk = 0; kk < 8; ++kk)
                    af[kk] = *(const half8*)(h2c + (kbase + kk) * 8192 + laneoff + cb * 256);
#pragma unroll
                for (int kk = 0; kk < 8; ++kk)
#pragma unroll
                    for (int nt = 0; nt < 4; ++nt)
                        acc[nt] = __builtin_amdgcn_mfma_f32_16x16x32_f16(af[kk], wfr[nt][kk], acc[nt], 0, 0, 0);
#pragma unroll
                for (int r = 0; r < 4; ++r) {
                    if (w != r) *(float4_*)&redbuf[(w * 64 + lane) * 4] = acc[r];
                    __syncthreads();
                    if (w == r) {
#pragma unroll
                        for (int wo = 0; wo < 4; ++wo) if (wo != r)
                            acc[r] += *(const float4_*)&redbuf[(wo * 64 + lane) * 4];
                    }
                    __syncthreads();
                }
                float4_ myy = acc[0];
#pragma unroll
                for (int r = 1; r < 4; ++r) if (w == r) myy = acc[r];
#pragma unroll
                for (int r = 0; r < 4; ++r) {
                    int m = cb * 16 + quad * 4 + r;
                    out[(size_t)m * 32768 + (size_t)t * 64 + (w * 16 + cl)] = myy[r] + bo_;
                }
            }
            slot_barrier(bar, (unsigned)(s + 1) * NBLK);
        }
    }
}

extern "C" void kernel_launch(void* const* d_in, const int* in_sizes, int n_in,
                              void* d_out, int out_size, void* d_ws, size_t ws_size,
                              hipStream_t stream) {
    const float* inp  = (const float*)d_in[0];
    const float* Wih1 = (const float*)d_in[1];
    const float* Whh1 = (const float*)d_in[2];
    const float* bih1 = (const float*)d_in[3];
    const float* bhh1 = (const float*)d_in[4];
    const float* Wih2 = (const float*)d_in[5];
    const float* Whh2 = (const float*)d_in[6];
    const float* bih2 = (const float*)d_in[7];
    const float* bhh2 = (const float*)d_in[8];
    const float* Wout = (const float*)d_in[9];
    const float* bout = (const float*)d_in[10];
    char* ws = (char*)d_ws;

    // zero barrier counter + both phases of H1/H2 (ws is poisoned before every call)
    hipMemsetAsync(d_ws, 0, ZERO_BYTES, stream);
    prep_x<<<TSTEPS, 256, 0, stream>>>(inp, ws);
    lstm_persistent<<<NBLK, 256, 0, stream>>>(Wih1, Whh1, bih1, bhh1,
                                              Wih2, Whh2, bih2, bhh2,
                                              Wout, bout, ws, (float*)d_out);
}